// Round 11
// baseline (207.600 us; speedup 1.0000x reference)
//
#include <hip/hip_runtime.h>
#include <math.h>

#define MAGIC 0x3C96A5F1
#define NGRU 8
#define NWRK 240
#define NBLK (NGRU + NWRK)   // 248 blocks, ~122KB LDS -> 1 block/CU, all co-resident
#define WSTR 260             // whh LDS row stride (floats)
#define ATAG 7u
#define FTAG 9u
#define LTAG 11u

__device__ __forceinline__ float sigmf(float x) { return 1.0f / (1.0f + expf(-x)); }

__device__ __forceinline__ void st_agent(float* p, float v) {
    __hip_atomic_store(p, v, __ATOMIC_RELAXED, __HIP_MEMORY_SCOPE_AGENT);
}
__device__ __forceinline__ void st_flag(int* p) {
    __hip_atomic_store(p, MAGIC, __ATOMIC_RELEASE, __HIP_MEMORY_SCOPE_AGENT);
}
// sleepy flag poll: for throughput barriers
__device__ __forceinline__ void poll_flags_s(const int* f, int n, int tid) {
    if (tid < n) {
        while (__hip_atomic_load(f + tid, __ATOMIC_RELAXED, __HIP_MEMORY_SCOPE_AGENT) != MAGIC)
            __builtin_amdgcn_s_sleep(2);
    }
    __builtin_amdgcn_fence(__ATOMIC_ACQUIRE, "agent");
    __syncthreads();
}
// single-word publish: (tag<<32)|bits — value rides with the tag, no fence needed
__device__ __forceinline__ void st_pk(unsigned long long* p, unsigned tag, float v) {
    __hip_atomic_store(p, ((unsigned long long)tag << 32) | (unsigned long long)__float_as_uint(v),
                       __ATOMIC_RELAXED, __HIP_MEMORY_SCOPE_AGENT);
}
__device__ __forceinline__ float poll_pk(const unsigned long long* p, unsigned tag) {
    unsigned long long v;
    do { v = __hip_atomic_load(p, __ATOMIC_RELAXED, __HIP_MEMORY_SCOPE_AGENT); }
    while ((unsigned)(v >> 32) != tag);
    return __uint_as_float((unsigned)(v & 0xffffffffu));
}
__device__ __forceinline__ float poll_pk_s(const unsigned long long* p, unsigned tag) {
    unsigned long long v = __hip_atomic_load(p, __ATOMIC_RELAXED, __HIP_MEMORY_SCOPE_AGENT);
    while ((unsigned)(v >> 32) != tag) {
        __builtin_amdgcn_s_sleep(1);
        v = __hip_atomic_load(p, __ATOMIC_RELAXED, __HIP_MEMORY_SCOPE_AGENT);
    }
    return __uint_as_float((unsigned)(v & 0xffffffffu));
}

__global__ __launch_bounds__(256) void mega_k(
    const float* __restrict__ x, const int* __restrict__ inst, const int* __restrict__ tx,
    const float* __restrict__ hx, const float* __restrict__ cx,
    const float* __restrict__ conv1_w, const float* __restrict__ conv1_b,
    const float* __restrict__ conv2_w, const float* __restrict__ conv2_b,
    const float* __restrict__ conv3_w, const float* __restrict__ conv3_b,
    const float* __restrict__ emb,
    const float* __restrict__ wih, const float* __restrict__ whh,
    const float* __restrict__ bih, const float* __restrict__ bhh,
    const float* __restrict__ attn_w, const float* __restrict__ attn_b,
    const float* __restrict__ time_emb,
    const float* __restrict__ lin_w, const float* __restrict__ lin_b,
    const float* __restrict__ lstm_wih, const float* __restrict__ lstm_whh,
    const float* __restrict__ lstm_bih, const float* __restrict__ lstm_bhh,
    const float* __restrict__ critic_w, const float* __restrict__ critic_b,
    const float* __restrict__ actor_w, const float* __restrict__ actor_b,
    float* __restrict__ c1o, float* __restrict__ c2o, float* __restrict__ img,
    unsigned long long* __restrict__ hpk,   // [18*256] (tag t+1)
    unsigned long long* __restrict__ apk,   // [320]
    unsigned long long* __restrict__ fpk,   // [256]
    unsigned long long* __restrict__ lpk,   // [1024]
    int* __restrict__ flags,                // c1f[240] c2f[240] imgf[64]
    float* __restrict__ out) {

    int* c1f  = flags;
    int* c2f  = flags + 240;
    int* imgf = flags + 480;

    __shared__ __align__(16) float whh_s[96 * WSTR]; // 97.5 KB; reused for lin_w at tail
    __shared__ float gi_s[18 * 96];
    __shared__ float wt_all[18 * 32];
    __shared__ float bhh_s[96];
    __shared__ __align__(16) float h_s[256];
    __shared__ __align__(16) float attn_s[320];
    __shared__ __align__(16) float av_s[680];
    __shared__ __align__(16) float f2_s[288];
    __shared__ __align__(16) float ws[2048];      // conv weight staging (workers)
    __shared__ __align__(16) float feat_ls[256];  // feat staged (workers)

    const int tid = threadIdx.x;
    const int b = blockIdx.x;

    // ---- mass prefetch: front-load ALL cold HBM lines into LLC at full parallelism.
    // SDMA input-restore bypasses caches each replay -> demand misses otherwise
    // serialize phases at ~900cy/line (~130 GB/s observed). ~21 f4 loads/thread.
    {
        const int gthr = NBLK * 256;
        const int gid = b * 256 + tid;
        float acc = 0.f;
        #define PF(ptr, nf) for (int i = gid; i < ((nf) >> 2); i += gthr) { \
            float4 v = reinterpret_cast<const float4*>(ptr)[i]; \
            acc += v.x + v.y + v.z + v.w; }
        PF(whh, 196608)        // 768x256 — GRU LDS stage hits LLC
        PF(x, 151200)          // conv1 input
        PF(conv2_w, 131072)
        PF(lstm_wih, 262144)
        PF(lstm_whh, 262144)
        PF(lin_w, 174080)
        PF(attn_w, 81920)
        PF(conv3_w, 65536)
        PF(wih, 24576)
        PF(emb, 9600)
        #undef PF
        asm volatile("" :: "v"(acc));   // keep loads live
    }

    if (b < NGRU) {
        // ============== GRU path: block owns h-dims [b*32, b*32+32) ==============
        const int d = tid >> 3;          // dim within slice
        const int ch = tid & 7;          // 8 col-chunks of 32
        const int dimg = b * 32 + d;

        // stage whh rows (r,z,g of my dims) into LDS, coalesced float4
        for (int i = tid; i < 96 * 64; i += 256) {
            int lr = i >> 6, q = i & 63;
            int gr = (lr >> 5) * 256 + b * 32 + (lr & 31);
            float4 v = *reinterpret_cast<const float4*>(whh + gr * 256 + q * 4);
            *reinterpret_cast<float4*>(&whh_s[lr * WSTR + q * 4]) = v;
        }
        for (int i = tid; i < 18 * 32; i += 256) wt_all[i] = emb[inst[i >> 5] * 32 + (i & 31)];
        if (tid < 96) bhh_s[tid] = bhh[(tid >> 5) * 256 + b * 32 + (tid & 31)];
        h_s[tid] = 0.0f;
        __syncthreads();

        // gi precompute (h-independent): gi_s[t*96 + gate*32 + j]
        for (int u = tid; u < 18 * 96; u += 256) {
            int t = u / 96, r = u % 96;
            int R = (r >> 5) * 256 + b * 32 + (r & 31);
            const float4* w4 = reinterpret_cast<const float4*>(wih + R * 32);
            const float4* e4 = reinterpret_cast<const float4*>(wt_all + t * 32);
            float s = 0.f;
            #pragma unroll
            for (int q = 0; q < 8; q++) {
                float4 a = w4[q], c = e4[q];
                s += a.x * c.x + a.y * c.y + a.z * c.z + a.w * c.w;
            }
            gi_s[u] = s + bih[R];
        }
        __syncthreads();

        // ---- 18 GRU steps: one packet RTT each ----
        for (int t = 0; t < 18; t++) {
            const float4* hr4 = reinterpret_cast<const float4*>(h_s + ch * 32);
            const float4* w0 = reinterpret_cast<const float4*>(&whh_s[d * WSTR + ch * 32]);
            const float4* w1 = reinterpret_cast<const float4*>(&whh_s[(32 + d) * WSTR + ch * 32]);
            const float4* w2 = reinterpret_cast<const float4*>(&whh_s[(64 + d) * WSTR + ch * 32]);
            float p0 = 0.f, p1 = 0.f, p2 = 0.f;
            #pragma unroll
            for (int j = 0; j < 8; j++) {
                float4 c = hr4[j];
                float4 a0 = w0[j], a1 = w1[j], a2 = w2[j];
                p0 += a0.x * c.x + a0.y * c.y + a0.z * c.z + a0.w * c.w;
                p1 += a1.x * c.x + a1.y * c.y + a1.z * c.z + a1.w * c.w;
                p2 += a2.x * c.x + a2.y * c.y + a2.z * c.z + a2.w * c.w;
            }
            p0 += __shfl_xor(p0, 1); p0 += __shfl_xor(p0, 2); p0 += __shfl_xor(p0, 4);
            p1 += __shfl_xor(p1, 1); p1 += __shfl_xor(p1, 2); p1 += __shfl_xor(p1, 4);
            p2 += __shfl_xor(p2, 1); p2 += __shfl_xor(p2, 2); p2 += __shfl_xor(p2, 4);
            if (ch == 0) {
                float ghr = p0 + bhh_s[d];
                float ghz = p1 + bhh_s[32 + d];
                float ghg = p2 + bhh_s[64 + d];
                float rr = sigmf(gi_s[t * 96 + d] + ghr);
                float zz = sigmf(gi_s[t * 96 + 32 + d] + ghz);
                float gg = tanhf(gi_s[t * 96 + 64 + d] + rr * ghg);
                float hn = (1.f - zz) * gg + zz * h_s[dimg];
                st_pk(hpk + t * 256 + dimg, (unsigned)(t + 1), hn);
            }
            float hv = poll_pk(hpk + t * 256 + tid, (unsigned)(t + 1));
            __syncthreads();          // all matvec reads of old h_s done
            h_s[tid] = hv;
            __syncthreads();
        }

        // ---- attention rows [b*40, b*40+40): 4 threads/row ----
        {
            int lr = tid >> 2, ln = tid & 3;
            if (lr < 40) {
                int a = b * 40 + lr;
                const float4* w4 = reinterpret_cast<const float4*>(attn_w + a * 256 + ln * 64);
                const float4* h4 = reinterpret_cast<const float4*>(h_s + ln * 64);
                float s = 0.f;
                #pragma unroll
                for (int q = 0; q < 16; q++) {
                    float4 aa = w4[q], cc = h4[q];
                    s += aa.x * cc.x + aa.y * cc.y + aa.z * cc.z + aa.w * cc.w;
                }
                s += __shfl_xor(s, 1); s += __shfl_xor(s, 2);
                if (ln == 0) st_pk(apk + a, ATAG, fmaxf(s + attn_b[a], 0.f));
            }
        }
        // ---- stage my lin_w rows into dead whh_s (hides fetch under apk RTT) ----
        {
            const float4* lw = reinterpret_cast<const float4*>(lin_w + b * 32 * 680);
            float4* dst = reinterpret_cast<float4*>(whh_s);
            for (int i = tid; i < 32 * 170; i += 256) dst[i] = lw[i];
        }
        // ---- stage attn packets + wait img flags ----
        attn_s[tid] = poll_pk(apk + tid, ATAG);
        if (tid < 64) attn_s[256 + tid] = poll_pk(apk + 256 + tid, ATAG);
        if (tid < 64) {
            while (__hip_atomic_load(imgf + tid, __ATOMIC_RELAXED, __HIP_MEMORY_SCOPE_AGENT) != MAGIC) {}
        }
        __builtin_amdgcn_fence(__ATOMIC_ACQUIRE, "agent");
        __syncthreads();

        // ---- redundant av (each GRU block computes all 680) ----
        for (int o = tid; o < 680; o += 256) {
            int k = o / 136, rem = o - k * 136;
            const float* ag = attn_s + k * 64;
            const float* ip = img + rem;
            float s = 0.f;
            #pragma unroll 8
            for (int c = 0; c < 64; c++) s = fmaf(ag[c], ip[c * 136], s);
            av_s[o] = s;
        }
        __syncthreads();

        // ---- feat rows [b*32,+32): 8 threads/row, lin_w from LDS ----
        {
            int lr = tid >> 3, ln = tid & 7;
            int fr = b * 32 + lr;
            const float4* w4 = reinterpret_cast<const float4*>(whh_s + lr * 680);
            const float4* a4 = reinterpret_cast<const float4*>(av_s);
            float s = 0.f;
            for (int c = ln; c < 170; c += 8) {
                float4 a = w4[c], cc = a4[c];
                s += a.x * cc.x + a.y * cc.y + a.z * cc.z + a.w * cc.w;
            }
            s += __shfl_xor(s, 1); s += __shfl_xor(s, 2); s += __shfl_xor(s, 4);
            if (ln == 0) st_pk(fpk + fr, FTAG, fmaxf(s + lin_b[fr], 0.f));
        }

        // ---- block 0: LSTM cell + heads + scratch self-clean ----
        if (b == 0) {
            float ig = poll_pk(lpk + tid, LTAG);
            float fg = poll_pk(lpk + 256 + tid, LTAG);
            float gg = poll_pk(lpk + 512 + tid, LTAG);
            float og = poll_pk(lpk + 768 + tid, LTAG);
            float cc = sigmf(fg) * cx[tid] + sigmf(ig) * tanhf(gg);
            float hh = sigmf(og) * tanhf(cc);
            out[260 + tid] = cc;   // c2
            out[4 + tid] = hh;     // h2x
            f2_s[tid] = hh;
            if (tid < 32) f2_s[256 + tid] = time_emb[tx[0] * 32 + tid];
            __syncthreads();
            int wv = tid >> 6, ln = tid & 63;
            const float* wr = (wv == 0) ? critic_w : (actor_w + (wv - 1) * 288);
            float p = 0.f;
            for (int i = ln; i < 288; i += 64) p = fmaf(f2_s[i], wr[i], p);
            #pragma unroll
            for (int off = 32; off >= 1; off >>= 1) p += __shfl_down(p, off);
            if (ln == 0) out[wv] = p + ((wv == 0) ? critic_b[0] : actor_b[wv - 1]);
            // self-clean: all pollers of every flag/packet have provably passed
            __syncthreads();
            for (int i = tid; i < 544; i += 256) flags[i] = 0;
            for (int i = tid; i < 18 * 256; i += 256) hpk[i] = 0ull;
            for (int i = tid; i < 320; i += 256) apk[i] = 0ull;
            if (tid < 256) fpk[tid] = 0ull;
            for (int i = tid; i < 1024; i += 256) lpk[i] = 0ull;
        }
    } else {
        // ============== worker path: conv1 -> conv2 -> conv3 -> LSTM rows ==============
        const int wb = b - NGRU;   // 0..239

        // ---- conv1: 1536 (co, 256px-chunk) tiles ----
        for (int tile = wb; tile < 1536; tile += NWRK) {
            int co = tile / 12, chunk = tile % 12;
            __syncthreads();
            if (tid < 192) ws[tid] = conv1_w[co * 192 + tid];
            __syncthreads();
            int pix = chunk * 256 + tid;
            if (pix < 3034) {
                int oh = pix / 74, ow = pix % 74;
                const float* xp = x + oh * 4 * 300 + ow * 4;
                float acc = conv1_b[co];
                #pragma unroll
                for (int ci = 0; ci < 3; ci++) {
                    #pragma unroll
                    for (int kh = 0; kh < 8; kh++) {
                        const float* row = xp + ci * (168 * 300) + kh * 300;
                        const float* wr = ws + ci * 64 + kh * 8;
                        float4 q0 = *reinterpret_cast<const float4*>(row);
                        float4 q1 = *reinterpret_cast<const float4*>(row + 4);
                        acc += q0.x * wr[0] + q0.y * wr[1] + q0.z * wr[2] + q0.w * wr[3]
                             + q1.x * wr[4] + q1.y * wr[5] + q1.z * wr[6] + q1.w * wr[7];
                    }
                }
                st_agent(c1o + co * 3034 + pix, fmaxf(acc, 0.f));
            }
        }
        __syncthreads();
        if (tid == 0) st_flag(c1f + wb);
        poll_flags_s(c1f, NWRK, tid);

        // ---- conv2: 192 (co, 256px-chunk) tiles ----
        for (int tile = wb; tile < 192; tile += NWRK) {
            int co = tile / 3, chunk = tile % 3;
            __syncthreads();
            for (int i = tid; i < 2048; i += 256) ws[i] = conv2_w[co * 2048 + i];
            __syncthreads();
            int pix = chunk * 256 + tid;
            if (pix < 684) {
                int oh = pix / 36, ow = pix % 36;
                const float* base = c1o + oh * 2 * 74 + ow * 2;
                float acc = conv2_b[co];
                #pragma unroll 4
                for (int ci = 0; ci < 128; ci++) {
                    const float* ip = base + ci * 3034;
                    const float* wc = ws + ci * 16;
                    #pragma unroll
                    for (int kh = 0; kh < 4; kh++) {
                        const float* row = ip + kh * 74;
                        const float* wr = wc + kh * 4;
                        float2 a0 = *reinterpret_cast<const float2*>(row);
                        float2 a1 = *reinterpret_cast<const float2*>(row + 2);
                        acc += a0.x * wr[0] + a0.y * wr[1] + a1.x * wr[2] + a1.y * wr[3];
                    }
                }
                st_agent(c2o + co * 684 + pix, fmaxf(acc, 0.f));
            }
        }
        __syncthreads();
        if (tid == 0) st_flag(c2f + wb);

        if (wb < 64) {
            poll_flags_s(c2f, NWRK, tid);
            // ---- conv3: co = wb ----
            {
                int co = wb;
                for (int i = tid; i < 1024; i += 256) ws[i] = conv3_w[co * 1024 + i];
                __syncthreads();
                if (tid < 136) {
                    int oh = tid / 17, ow = tid % 17;
                    const float* base = c2o + oh * 2 * 36 + ow * 2;
                    float acc = conv3_b[co];
                    #pragma unroll 4
                    for (int ci = 0; ci < 64; ci++) {
                        const float* ip = base + ci * 684;
                        const float* wc = ws + ci * 16;
                        #pragma unroll
                        for (int kh = 0; kh < 4; kh++) {
                            const float* row = ip + kh * 36;
                            const float* wr = wc + kh * 4;
                            float2 a0 = *reinterpret_cast<const float2*>(row);
                            float2 a1 = *reinterpret_cast<const float2*>(row + 2);
                            acc += a0.x * wr[0] + a0.y * wr[1] + a1.x * wr[2] + a1.y * wr[3];
                        }
                    }
                    st_agent(img + co * 136 + tid, fmaxf(acc, 0.f));
                }
                __syncthreads();
                if (tid == 0) st_flag(imgf + wb);
            }
            // ---- LSTM prep BEFORE fpk wait: wi rows -> regs, wh·hx partial ----
            int lr = tid >> 4, ln = tid & 15;
            int r = wb * 16 + lr;
            const float4* wi4 = reinterpret_cast<const float4*>(lstm_wih + r * 256);
            const float4* wh4 = reinterpret_cast<const float4*>(lstm_whh + r * 256);
            const float4* x4 = reinterpret_cast<const float4*>(hx);
            float4 wi0 = wi4[ln * 4 + 0], wi1 = wi4[ln * 4 + 1];
            float4 wi2 = wi4[ln * 4 + 2], wi3 = wi4[ln * 4 + 3];
            float s = 0.f;
            #pragma unroll
            for (int q = 0; q < 4; q++) {
                float4 dd = wh4[ln * 4 + q], e = x4[ln * 4 + q];
                s += dd.x * e.x + dd.y * e.y + dd.z * e.z + dd.w * e.w;
            }
            float bsum = lstm_bih[r] + lstm_bhh[r];
            // ---- poll feat (light sleep), finish with registered wi ----
            feat_ls[tid] = poll_pk_s(fpk + tid, FTAG);
            __syncthreads();
            const float4* f4 = reinterpret_cast<const float4*>(feat_ls);
            float4 c0 = f4[ln * 4 + 0], c1 = f4[ln * 4 + 1];
            float4 c2 = f4[ln * 4 + 2], c3 = f4[ln * 4 + 3];
            s += wi0.x * c0.x + wi0.y * c0.y + wi0.z * c0.z + wi0.w * c0.w;
            s += wi1.x * c1.x + wi1.y * c1.y + wi1.z * c1.z + wi1.w * c1.w;
            s += wi2.x * c2.x + wi2.y * c2.y + wi2.z * c2.z + wi2.w * c2.w;
            s += wi3.x * c3.x + wi3.y * c3.y + wi3.z * c3.z + wi3.w * c3.w;
            s += __shfl_xor(s, 1); s += __shfl_xor(s, 2);
            s += __shfl_xor(s, 4); s += __shfl_xor(s, 8);
            if (ln == 0) st_pk(lpk + r, LTAG, s + bsum);
        }
    }
}

extern "C" void kernel_launch(void* const* d_in, const int* in_sizes, int n_in,
                              void* d_out, int out_size, void* d_ws, size_t ws_size,
                              hipStream_t stream) {
    const float* x        = (const float*)d_in[0];
    const int*   inst     = (const int*)d_in[1];
    const int*   tx       = (const int*)d_in[2];
    const float* hx       = (const float*)d_in[3];
    const float* cx       = (const float*)d_in[4];
    const float* conv1_w  = (const float*)d_in[5];
    const float* conv1_b  = (const float*)d_in[6];
    const float* conv2_w  = (const float*)d_in[7];
    const float* conv2_b  = (const float*)d_in[8];
    const float* conv3_w  = (const float*)d_in[9];
    const float* conv3_b  = (const float*)d_in[10];
    const float* emb      = (const float*)d_in[11];
    const float* gru_wih  = (const float*)d_in[12];
    const float* gru_whh  = (const float*)d_in[13];
    const float* gru_bih  = (const float*)d_in[14];
    const float* gru_bhh  = (const float*)d_in[15];
    const float* attn_w   = (const float*)d_in[16];
    const float* attn_b   = (const float*)d_in[17];
    const float* time_emb = (const float*)d_in[18];
    const float* lin_w    = (const float*)d_in[19];
    const float* lin_b    = (const float*)d_in[20];
    const float* lstm_wih = (const float*)d_in[21];
    const float* lstm_whh = (const float*)d_in[22];
    const float* lstm_bih = (const float*)d_in[23];
    const float* lstm_bhh = (const float*)d_in[24];
    const float* critic_w = (const float*)d_in[25];
    const float* critic_b = (const float*)d_in[26];
    const float* actor_w  = (const float*)d_in[27];
    const float* actor_b  = (const float*)d_in[28];

    float* wsf = (float*)d_ws;
    float* c1o  = wsf;                    // [388352]
    float* c2o  = wsf + 388352;           // [43776]
    float* img  = wsf + 432128;           // [8704]  -> ends 440832
    unsigned long long* hpk = (unsigned long long*)(wsf + 440832); // [18*256] u64
    unsigned long long* apk = (unsigned long long*)(wsf + 450048); // [320] u64
    unsigned long long* fpk = (unsigned long long*)(wsf + 450688); // [256] u64
    unsigned long long* lpk = (unsigned long long*)(wsf + 451200); // [1024] u64
    int* flags = (int*)(wsf + 453248);    // [544] ints
    float* out = (float*)d_out;           // [516] = critic(1)+actor(3)+h2x(256)+c2(256)

    mega_k<<<NBLK, 256, 0, stream>>>(x, inst, tx, hx, cx,
                                     conv1_w, conv1_b, conv2_w, conv2_b, conv3_w, conv3_b,
                                     emb, gru_wih, gru_whh, gru_bih, gru_bhh,
                                     attn_w, attn_b, time_emb, lin_w, lin_b,
                                     lstm_wih, lstm_whh, lstm_bih, lstm_bhh,
                                     critic_w, critic_b, actor_w, actor_b,
                                     c1o, c2o, img, hpk, apk, fpk, lpk,
                                     flags, out);
}